// Round 15
// baseline (180.501 us; speedup 1.0000x reference)
//
#include <hip/hip_runtime.h>
#include <math.h>

#define BB   8
#define NN   1024
#define SS   128
#define KK   32
#define EMB  384

// padded K strides (elements) for transposed f16 weights
#define KP1  136   // W1bt [256][136]
#define KP2  264   // W2at [512][264]
#define KP3  520   // W2bt [384][520]

// LDS float4-cloud swizzle: XOR low3 with bits3-5 (bijective involution).
#define SWZ(i) ((i) ^ (((i) >> 3) & 7))

typedef __attribute__((ext_vector_type(4))) float f32x4;
typedef __attribute__((ext_vector_type(8))) _Float16 f16x8;

__device__ __forceinline__ f32x4 mfma16h(f16x8 a, f16x8 b, f32x4 c) {
    return __builtin_amdgcn_mfma_f32_16x16x32_f16(a, b, c, 0, 0, 0);
}
__device__ __forceinline__ f32x4 vmax4(f32x4 a, f32x4 b) {
    f32x4 r;
    r.x = fmaxf(a.x, b.x); r.y = fmaxf(a.y, b.y);
    r.z = fmaxf(a.z, b.z); r.w = fmaxf(a.w, b.w);
    return r;
}

// ---------------------------------------------------------------------------
// FPS: 256 threads/cloud. ONE barrier/iter; reduce split so the expensive
// 64-value broadcast runs PER-WAVE (4 SIMDs in parallel), and the
// post-barrier stage is just a 4-way register argmax over s_fin.
//   - (best,bi) stay in registers (no s_idx array, no 256-pair read stage)
//   - wave w: write 64 bests -> s_red[w] (private), 16 x b128 broadcast +
//     vmax tree -> wmax; ballot+ffs+readlane -> (wmax, widx). Lane order =
//     index order -> lowest set lane = lowest index.
//   - lane0 writes (wmax,widx) to s_fin[par] (parity double-buffer kills the
//     cross-iteration race); barrier; ALL threads read 4 pairs (2 uniform
//     b128) and argmax with strict > ascending wave -> lowest idx ties.
// Selection bit-identical to rounds 7-14 (same dist arithmetic, same total
// order: global argmax, ties -> lowest index).
// ---------------------------------------------------------------------------
__global__ __launch_bounds__(256) void fps_kernel(
    const float* __restrict__ pos, float* __restrict__ seed_pos)
{
    __shared__ __align__(16) float4 s_cloud4[NN];     // 16 KB, swizzled
    __shared__ __align__(16) float  s_red[4][64];     // per-wave private
    __shared__ __align__(16) float  s_fv[2][4];       // wave maxima (parity)
    __shared__ __align__(16) int    s_fi[2][4];       // wave arg indices

    const int b = blockIdx.x;
    const int t = threadIdx.x;
    const int w = t >> 6;
    const int l = t & 63;
    const float* p = pos + (size_t)b * NN * 3;

    for (int i = t; i < NN; i += 256) {
        float4 q;
        q.x = p[i * 3 + 0];
        q.y = p[i * 3 + 1];
        q.z = p[i * 3 + 2];
        q.w = 0.0f;
        s_cloud4[SWZ(i)] = q;
    }
    __syncthreads();

    float mind[4] = {INFINITY, INFINITY, INFINITY, INFINITY};
    float4 sc = s_cloud4[SWZ(0)];                     // seed 0 coords
    for (int s = 0; s < SS; ++s) {
        if (t == 0) {
            seed_pos[((size_t)b * SS + s) * 3 + 0] = sc.x;
            seed_pos[((size_t)b * SS + s) * 3 + 1] = sc.y;
            seed_pos[((size_t)b * SS + s) * 3 + 2] = sc.z;
        }
        if (s == SS - 1) break;
        const int par = s & 1;

        // dist update + per-thread argmax (ascending r, strict > -> lowest idx)
        float best = -INFINITY;
        int bi = 0;
#pragma unroll
        for (int r = 0; r < 4; ++r) {
            const float4 q = s_cloud4[SWZ(t * 4 + r)];
            const float dx = __fsub_rn(q.x, sc.x);
            const float dy = __fsub_rn(q.y, sc.y);
            const float dz = __fsub_rn(q.z, sc.z);
            const float d = __fadd_rn(__fadd_rn(__fmul_rn(dx, dx), __fmul_rn(dy, dy)),
                                      __fmul_rn(dz, dz));
            mind[r] = fminf(mind[r], d);
            if (mind[r] > best) { best = mind[r]; bi = t * 4 + r; }
        }

        // per-wave reduce (runs on all 4 SIMDs in parallel)
        s_red[w][l] = best;
        const f32x4* rp = (const f32x4*)&s_red[w][0];
        const f32x4 u0 = vmax4(vmax4(rp[0],  rp[1]),  vmax4(rp[2],  rp[3]));
        const f32x4 u1 = vmax4(vmax4(rp[4],  rp[5]),  vmax4(rp[6],  rp[7]));
        const f32x4 u2 = vmax4(vmax4(rp[8],  rp[9]),  vmax4(rp[10], rp[11]));
        const f32x4 u3 = vmax4(vmax4(rp[12], rp[13]), vmax4(rp[14], rp[15]));
        const f32x4 uu = vmax4(vmax4(u0, u1), vmax4(u2, u3));
        const float wmax = fmaxf(fmaxf(uu.x, uu.y), fmaxf(uu.z, uu.w));
        // lowest set lane = lowest thread = lowest point range
        const unsigned long long mb = __ballot(best == wmax);
        const int ln = (int)__ffsll(mb) - 1;
        const int widx = __builtin_amdgcn_readlane(bi, ln);
        if (l == 0) {
            s_fv[par][w] = wmax;
            s_fi[par][w] = widx;
        }
        __syncthreads();                              // the ONLY barrier

        // all threads: 4-way argmax (strict >, ascending wave -> lowest idx)
        const f32x4 fv = *(const f32x4*)&s_fv[par][0];
        const int4  fi = *(const int4*)&s_fi[par][0];
        float gv = fv.x; int gi = fi.x;
        if (fv.y > gv) { gv = fv.y; gi = fi.y; }
        if (fv.z > gv) { gv = fv.z; gi = fi.z; }
        if (fv.w > gv) { gv = fv.w; gi = fi.w; }
        sc = s_cloud4[SWZ(gi)];                       // uniform broadcast read
    }
}

// ---------------------------------------------------------------------------
// knn_prep: blocks 0..127 = kNN (verified rounds 3-14, logic untouched);
// blocks 128..303 = weight transpose + f16 convert, 2 tiles per 512-thr block.
// ---------------------------------------------------------------------------
__global__ __launch_bounds__(512) void knn_prep_kernel(
    const float* __restrict__ pos,
    const float* __restrict__ seed_pos,
    int* __restrict__ nbr,
    const float* __restrict__ W1b, const float* __restrict__ W2a,
    const float* __restrict__ W2b,
    _Float16* __restrict__ W1bt, _Float16* __restrict__ W2at,
    _Float16* __restrict__ W2bt)
{
    __shared__ float sx_[NN], sy_[NN], sz_[NN];
    __shared__ float tile[2][32][33];
    const int bid = blockIdx.x;
    const int t   = threadIdx.x;

    if (bid < 128) {
        const int blk = bid;
        const int b   = blk >> 4;
        const int w   = t >> 6;
        const int l   = t & 63;
        const float* p = pos + (size_t)b * NN * 3;

        for (int i = t; i < NN; i += 512) {
            sx_[i] = p[i * 3 + 0];
            sy_[i] = p[i * 3 + 1];
            sz_[i] = p[i * 3 + 2];
        }
        __syncthreads();

        const int gsid = b * SS + (blk & 15) * 8 + w;
        const float cx = seed_pos[gsid * 3 + 0];
        const float cy = seed_pos[gsid * 3 + 1];
        const float cz = seed_pos[gsid * 3 + 2];

        float d[16];
#pragma unroll
        for (int r = 0; r < 16; ++r) {
            const int i = r * 64 + l;
            const float dx = __fsub_rn(sx_[i], cx);
            const float dy = __fsub_rn(sy_[i], cy);
            const float dz = __fsub_rn(sz_[i], cz);
            d[r] = __fadd_rn(__fadd_rn(__fmul_rn(dx, dx), __fmul_rn(dy, dy)),
                             __fmul_rn(dz, dz));
        }

        for (int it = 0; it < KK; ++it) {
            float best = INFINITY;
            int bi = NN;
#pragma unroll
            for (int r = 0; r < 16; ++r) {
                if (d[r] < best) { best = d[r]; bi = r * 64 + l; }
            }
#pragma unroll
            for (int off = 1; off < 64; off <<= 1) {
                const float ov = __shfl_xor(best, off);
                const int   oi = __shfl_xor(bi, off);
                if (ov < best || (ov == best && oi < bi)) { best = ov; bi = oi; }
            }
            const int wr = bi >> 6, wl = bi & 63;
#pragma unroll
            for (int r = 0; r < 16; ++r) {
                if (r == wr && l == wl) d[r] = INFINITY;
            }
            if (l == 0) nbr[(size_t)gsid * KK + it] = bi;
        }
        return;
    }

    // ---------------- weight prep: 2 tiles per block ----------------
    const int half = t >> 8;
    const int tt   = t & 255;
    int tid = (bid - 128) * 2 + half;
    const float* src;
    _Float16* dh;
    int N, Kp, koff, kt, nt;
    if (tid < 32) {
        src = W1b; dh = W1bt; N = 256; Kp = KP1; koff = 0;
        kt = tid >> 3; nt = tid & 7;
    } else if (tid < 160) {
        tid -= 32;
        src = W2a; dh = W2at; N = 512; Kp = KP2; koff = 256;
        kt = tid >> 4; nt = tid & 15;
    } else {
        tid -= 160;
        src = W2b; dh = W2bt; N = 384; Kp = KP3; koff = 0;
        kt = tid / 12; nt = tid % 12;
    }
    const int k0 = kt * 32, n0 = nt * 32;
    const int tx = tt & 31, ty = tt >> 5;
#pragma unroll
    for (int i = 0; i < 4; ++i) {
        const int kl = ty + i * 8;
        tile[half][kl][tx] = src[(size_t)(k0 + kl + koff) * N + n0 + tx];
    }
    __syncthreads();
#pragma unroll
    for (int i = 0; i < 4; ++i) {
        const int nl = ty + i * 8;
        dh[(size_t)(n0 + nl) * Kp + k0 + tx] = (_Float16)tile[half][tx][nl];
    }
}

// ---------------------------------------------------------------------------
// PointConv, M=128 (4 seeds/block), 1024 threads = 16 waves, f16 operands.
// Verified round 9; byte-identical to rounds 13-14.
// ---------------------------------------------------------------------------
__global__ __launch_bounds__(1024) void conv_kernel(
    const float* __restrict__ pos,
    const float* __restrict__ seed_pos,
    const int* __restrict__ nbr,
    const float* __restrict__ W1a, const float* __restrict__ b1a,
    const float* __restrict__ b1b,
    const float* __restrict__ W2a, const float* __restrict__ b2a,
    const float* __restrict__ b2b,
    const _Float16* __restrict__ W1bt, const _Float16* __restrict__ W2at,
    const _Float16* __restrict__ W2bt,
    float* __restrict__ out)
{
    __shared__ __align__(16) unsigned char smem[144896];
    unsigned char* sBig = smem;                 // rotating region
    float* s_g    = (float*)(smem + 131072);    // [4][256]
    float* s_base = (float*)(smem + 135168);    // [4][512]
    float* s_rel  = (float*)(smem + 143360);    // [128][3]

    const int blk = blockIdx.x;                 // seeds blk*4 .. blk*4+3
    const int t   = threadIdx.x;
    const int w   = t >> 6;                     // wave 0..15
    const int l   = t & 63;
    const int lg  = l >> 4;
    const int l15 = l & 15;

    // ---- stage 0: gather rel for 128 rows (4 seeds x 32 neighbors) ----
    if (t < 128) {
        const int sl   = t >> 5;
        const int gsid = blk * 4 + sl;
        const int b    = gsid >> 7;
        const int pi   = nbr[(size_t)gsid * KK + (t & 31)];
        const float* pp = pos + ((size_t)b * NN + pi) * 3;
        s_rel[t * 3 + 0] = pp[0] - seed_pos[gsid * 3 + 0];
        s_rel[t * 3 + 1] = pp[1] - seed_pos[gsid * 3 + 1];
        s_rel[t * 3 + 2] = pp[2] - seed_pos[gsid * 3 + 2];
    }
    __syncthreads();

    // ---- stage 1: h1[128][128] = relu(rel@W1a + b1a) -> f16 swizzled ----
    {
        const int j  = t & 127;
        const int rg = t >> 7;                  // 0..7, 16 rows each
        const float w0 = W1a[j], w1 = W1a[128 + j], w2 = W1a[256 + j], bb = b1a[j];
#pragma unroll
        for (int rr = 0; rr < 16; ++rr) {
            const int row = rg * 16 + rr;
            float v = fmaf(s_rel[row * 3 + 2], w2,
                      fmaf(s_rel[row * 3 + 1], w1,
                      fmaf(s_rel[row * 3 + 0], w0, bb)));
            v = fmaxf(v, 0.0f);
            const int byte = (j * 2) ^ ((row & 7) << 4);
            *(_Float16*)(sBig + row * 256 + byte) = (_Float16)v;
        }
    }
    __syncthreads();

    // ---- GEMM1: f = h1 @ W1b (M=128,N=256,K=128); wave w owns cols w*16+ ----
    f32x4 C1[8];
#pragma unroll
    for (int m = 0; m < 8; ++m) C1[m] = (f32x4){0.f, 0.f, 0.f, 0.f};
#pragma unroll
    for (int ks = 0; ks < 4; ++ks) {
        const int ncol = w * 16 + l15;
        const f16x8 bh = *(const f16x8*)(W1bt + (size_t)ncol * KP1 + lg * 8 + ks * 32);
#pragma unroll
        for (int m = 0; m < 8; ++m) {
            const int row = m * 16 + l15;
            const int byte = (lg * 16 + ks * 64) ^ ((row & 7) << 4);
            const f16x8 ah = *(const f16x8*)(sBig + row * 256 + byte);
            C1[m] = mfma16h(ah, bh, C1[m]);
        }
    }
    // per-seed colmax -> s_g (f32)
    {
        const int col = w * 16 + l15;
        const float bias = b1b[col];
        float pm0 = -INFINITY, pm1 = -INFINITY, pm2 = -INFINITY, pm3 = -INFINITY;
#pragma unroll
        for (int m = 0; m < 8; ++m)
#pragma unroll
            for (int r = 0; r < 4; ++r) {
                const float v = C1[m][r] + bias;
                if (m < 2)      pm0 = fmaxf(pm0, v);
                else if (m < 4) pm1 = fmaxf(pm1, v);
                else if (m < 6) pm2 = fmaxf(pm2, v);
                else            pm3 = fmaxf(pm3, v);
            }
        pm0 = fmaxf(pm0, __shfl_xor(pm0, 16)); pm0 = fmaxf(pm0, __shfl_xor(pm0, 32));
        pm1 = fmaxf(pm1, __shfl_xor(pm1, 16)); pm1 = fmaxf(pm1, __shfl_xor(pm1, 32));
        pm2 = fmaxf(pm2, __shfl_xor(pm2, 16)); pm2 = fmaxf(pm2, __shfl_xor(pm2, 32));
        pm3 = fmaxf(pm3, __shfl_xor(pm3, 16)); pm3 = fmaxf(pm3, __shfl_xor(pm3, 32));
        if (lg == 0) {
            s_g[0 * 256 + col] = pm0;
            s_g[1 * 256 + col] = pm1;
            s_g[2 * 256 + col] = pm2;
            s_g[3 * 256 + col] = pm3;
        }
    }
    __syncthreads();   // all h1 reads done; s_g complete

    // ---- A2 write: f -> f16 [128][512B] (overwrites dead h1) ----
    {
        const int col = w * 16 + l15;
        const float bias = b1b[col];
#pragma unroll
        for (int m = 0; m < 8; ++m)
#pragma unroll
            for (int r = 0; r < 4; ++r) {
                const float v = C1[m][r] + bias;
                const int row = m * 16 + lg * 4 + r;
                const int byte = (col * 2) ^ ((row & 7) << 4);
                *(_Float16*)(sBig + row * 512 + byte) = (_Float16)v;
            }
    }

    // ---- base[seed][c] = b2a[c] + g_seed @ W2a[0:256]; 2 seeds/thread ----
    {
        const int col = t & 511;
        const int sp  = t >> 9;                 // 0 -> seeds 0,1 ; 1 -> seeds 2,3
        float a0 = b2a[col], a1 = b2a[col];
        const float* g0 = s_g + (sp * 2) * 256;
        const float* g1 = s_g + (sp * 2 + 1) * 256;
#pragma unroll 4
        for (int jj = 0; jj < 256; ++jj) {
            const float w_ = W2a[(size_t)jj * 512 + col];
            a0 = fmaf(g0[jj], w_, a0);
            a1 = fmaf(g1[jj], w_, a1);
        }
        s_base[(sp * 2) * 512 + col]     = a0;
        s_base[(sp * 2 + 1) * 512 + col] = a1;
    }
    __syncthreads();   // A2 + s_base complete

    // ---- GEMM2: C2 = f @ W2a[256:] (M=128,N=512,K=256); cols w*32+n*16 ----
    f32x4 C2[8][2];
#pragma unroll
    for (int m = 0; m < 8; ++m)
#pragma unroll
        for (int n = 0; n < 2; ++n) C2[m][n] = (f32x4){0.f, 0.f, 0.f, 0.f};
#pragma unroll 2
    for (int ks = 0; ks < 8; ++ks) {
        f16x8 bh[2];
#pragma unroll
        for (int n = 0; n < 2; ++n) {
            const int ncol = w * 32 + n * 16 + l15;
            bh[n] = *(const f16x8*)(W2at + (size_t)ncol * KP2 + lg * 8 + ks * 32);
        }
#pragma unroll
        for (int m = 0; m < 8; ++m) {
            const int row = m * 16 + l15;
            const int byte = (lg * 16 + ks * 64) ^ ((row & 7) << 4);
            const f16x8 ah = *(const f16x8*)(sBig + row * 512 + byte);
            C2[m][0] = mfma16h(ah, bh[0], C2[m][0]);
            C2[m][1] = mfma16h(ah, bh[1], C2[m][1]);
        }
    }
    __syncthreads();   // A2 fully read; region reusable for A3

    // ---- A3 write: h2 = relu(C2 + base) -> f16 [128][1024B] ----
#pragma unroll
    for (int n = 0; n < 2; ++n) {
        const int col = w * 32 + n * 16 + l15;
#pragma unroll
        for (int m = 0; m < 8; ++m) {
            const float bs = s_base[(m >> 1) * 512 + col];
#pragma unroll
            for (int r = 0; r < 4; ++r) {
                const float v = fmaxf(C2[m][n][r] + bs, 0.0f);
                const int row = m * 16 + lg * 4 + r;
                const int byte = (col * 2) ^ ((row & 7) << 4);
                *(_Float16*)(sBig + row * 1024 + byte) = (_Float16)v;
            }
        }
    }
    __syncthreads();   // A3 complete

    // ---- GEMM3: e = h2 @ W2b (M=128,N=384,K=512); waves 0-11, no K-split ----
    if (w < 12) {
        f32x4 C3[8][2];
#pragma unroll
        for (int m = 0; m < 8; ++m)
#pragma unroll
            for (int n = 0; n < 2; ++n) C3[m][n] = (f32x4){0.f, 0.f, 0.f, 0.f};
#pragma unroll 2
        for (int ks = 0; ks < 16; ++ks) {
            f16x8 bh[2];
#pragma unroll
            for (int n = 0; n < 2; ++n) {
                const int ncol = w * 32 + n * 16 + l15;
                bh[n] = *(const f16x8*)(W2bt + (size_t)ncol * KP3 + lg * 8 + ks * 32);
            }
#pragma unroll
            for (int m = 0; m < 8; ++m) {
                const int row = m * 16 + l15;
                const int byte = (lg * 16 + ks * 64) ^ ((row & 7) << 4);
                const f16x8 ah = *(const f16x8*)(sBig + row * 1024 + byte);
                C3[m][0] = mfma16h(ah, bh[0], C3[m][0]);
                C3[m][1] = mfma16h(ah, bh[1], C3[m][1]);
            }
        }
        // epilogue: out[seed] = colmax(e_seed) + b2b
#pragma unroll
        for (int n = 0; n < 2; ++n) {
            const int col = w * 32 + n * 16 + l15;
            float pm0 = -INFINITY, pm1 = -INFINITY, pm2 = -INFINITY, pm3 = -INFINITY;
#pragma unroll
            for (int m = 0; m < 8; ++m)
#pragma unroll
                for (int r = 0; r < 4; ++r) {
                    const float v = C3[m][n][r];
                    if (m < 2)      pm0 = fmaxf(pm0, v);
                    else if (m < 4) pm1 = fmaxf(pm1, v);
                    else if (m < 6) pm2 = fmaxf(pm2, v);
                    else            pm3 = fmaxf(pm3, v);
                }
            pm0 = fmaxf(pm0, __shfl_xor(pm0, 16)); pm0 = fmaxf(pm0, __shfl_xor(pm0, 32));
            pm1 = fmaxf(pm1, __shfl_xor(pm1, 16)); pm1 = fmaxf(pm1, __shfl_xor(pm1, 32));
            pm2 = fmaxf(pm2, __shfl_xor(pm2, 16)); pm2 = fmaxf(pm2, __shfl_xor(pm2, 32));
            pm3 = fmaxf(pm3, __shfl_xor(pm3, 16)); pm3 = fmaxf(pm3, __shfl_xor(pm3, 32));
            if (lg == 0) {
                const float bb = b2b[col];
                out[(size_t)(blk * 4 + 0) * EMB + col] = pm0 + bb;
                out[(size_t)(blk * 4 + 1) * EMB + col] = pm1 + bb;
                out[(size_t)(blk * 4 + 2) * EMB + col] = pm2 + bb;
                out[(size_t)(blk * 4 + 3) * EMB + col] = pm3 + bb;
            }
        }
    }
}

// ---------------------------------------------------------------------------
extern "C" void kernel_launch(void* const* d_in, const int* in_sizes, int n_in,
                              void* d_out, int out_size, void* d_ws, size_t ws_size,
                              hipStream_t stream)
{
    const float* pos = (const float*)d_in[0];
    const float* W1a = (const float*)d_in[2];
    const float* b1a = (const float*)d_in[3];
    const float* W1b = (const float*)d_in[4];
    const float* b1b = (const float*)d_in[5];
    const float* W2a = (const float*)d_in[6];
    const float* b2a = (const float*)d_in[7];
    const float* W2b = (const float*)d_in[8];
    const float* b2b = (const float*)d_in[9];
    float* out = (float*)d_out;

    unsigned char* ws = (unsigned char*)d_ws;
    float* seed_pos = (float*)(ws + 0);                  // 12 KB
    int*   nbr      = (int*)(ws + 16384);                // 128 KB
    _Float16* W1bt  = (_Float16*)(ws + 147456);          // [256][136] 69632 B
    _Float16* W2at  = (_Float16*)(ws + 217088);          // [512][264] 270336 B
    _Float16* W2bt  = (_Float16*)(ws + 487424);          // [384][520] 399360 B

    fps_kernel<<<BB, 256, 0, stream>>>(pos, seed_pos);
    knn_prep_kernel<<<128 + 176, 512, 0, stream>>>(pos, seed_pos, nbr,
                                                   W1b, W2a, W2b,
                                                   W1bt, W2at, W2bt);
    conv_kernel<<<BB * SS / 4, 1024, 0, stream>>>(pos, seed_pos, nbr,
                                                  W1a, b1a, b1b, W2a, b2a, b2b,
                                                  W1bt, W2at, W2bt, out);
}

// Round 16
// 172.683 us; speedup vs baseline: 1.0453x; 1.0453x over previous
//
#include <hip/hip_runtime.h>
#include <math.h>

#define BB   8
#define NN   1024
#define SS   128
#define KK   32
#define EMB  384

// padded K strides (elements) for transposed f16 weights
#define KP1  136   // W1bt [256][136]
#define KP2  264   // W2at [512][264]
#define KP3  520   // W2bt [384][520]

// LDS float4-cloud swizzle: XOR low3 with bits3-5 (bijective involution).
#define SWZ(i) ((i) ^ (((i) >> 3) & 7))

typedef __attribute__((ext_vector_type(4))) float f32x4;
typedef __attribute__((ext_vector_type(8))) _Float16 f16x8;

__device__ __forceinline__ f32x4 mfma16h(f16x8 a, f16x8 b, f32x4 c) {
    return __builtin_amdgcn_mfma_f32_16x16x32_f16(a, b, c, 0, 0, 0);
}
__device__ __forceinline__ f32x4 vmax4(f32x4 a, f32x4 b) {
    f32x4 r;
    r.x = fmaxf(a.x, b.x); r.y = fmaxf(a.y, b.y);
    r.z = fmaxf(a.z, b.z); r.w = fmaxf(a.w, b.w);
    return r;
}

// ---------------------------------------------------------------------------
// fps_prep: blocks 0..7 = FPS (EXACT round-13 structure, measured 88 us —
// best of 8 variants; VGPR-light by design so fused prep can't starve it);
// blocks 8..359 = weight transpose + f16 convert (1 tile / 256-thr block),
// rides entirely in FPS's shadow on the other 248 CUs.
// Selection bit-identical to rounds 7-15.
// ---------------------------------------------------------------------------
__global__ __launch_bounds__(256) void fps_prep_kernel(
    const float* __restrict__ pos, float* __restrict__ seed_pos,
    const float* __restrict__ W1b, const float* __restrict__ W2a,
    const float* __restrict__ W2b,
    _Float16* __restrict__ W1bt, _Float16* __restrict__ W2at,
    _Float16* __restrict__ W2bt)
{
    __shared__ __align__(16) float4 s_cloud4[NN];   // 16 KB, swizzled
    __shared__ __align__(16) float  s_val[256];
    __shared__ __align__(16) int    s_idx[256];
    __shared__ __align__(16) float  s_red[64];
    __shared__ int s_gi;
    __shared__ float tile[32][33];                  // prep path

    const int bid = blockIdx.x;
    const int t = threadIdx.x;

    if (bid < BB) {
        // ---------------- FPS (round-13 verified, 88 us) ----------------
        const int b = bid;
        const float* p = pos + (size_t)b * NN * 3;

        for (int i = t; i < NN; i += 256) {
            float4 q;
            q.x = p[i * 3 + 0];
            q.y = p[i * 3 + 1];
            q.z = p[i * 3 + 2];
            q.w = 0.0f;
            s_cloud4[SWZ(i)] = q;
        }
        __syncthreads();

        float mind[4] = {INFINITY, INFINITY, INFINITY, INFINITY};
        int gi = 0;
        for (int s = 0; s < SS; ++s) {
            const float4 sc = s_cloud4[SWZ(gi)];    // uniform broadcast read
            if (t == 0) {
                seed_pos[((size_t)b * SS + s) * 3 + 0] = sc.x;
                seed_pos[((size_t)b * SS + s) * 3 + 1] = sc.y;
                seed_pos[((size_t)b * SS + s) * 3 + 2] = sc.z;
            }
            if (s == SS - 1) break;

            // dist update + local argmax (ascending r, strict > -> lowest idx)
            float best = -INFINITY;
            int bi = 0;
#pragma unroll
            for (int r = 0; r < 4; ++r) {
                const float4 q = s_cloud4[SWZ(t * 4 + r)];
                const float dx = __fsub_rn(q.x, sc.x);
                const float dy = __fsub_rn(q.y, sc.y);
                const float dz = __fsub_rn(q.z, sc.z);
                const float d = __fadd_rn(__fadd_rn(__fmul_rn(dx, dx), __fmul_rn(dy, dy)),
                                          __fmul_rn(dz, dz));
                mind[r] = fminf(mind[r], d);
                if (mind[r] > best) { best = mind[r]; bi = t * 4 + r; }
            }
            s_val[t] = best;
            s_idx[t] = bi;
            __syncthreads();

            if (t < 64) {                            // wave 0 only
                const f32x4 v4 = *(const f32x4*)&s_val[t * 4];
                const int4  i4 = *(const int4*)&s_idx[t * 4];
                float v = v4.x; int ci = i4.x;
                if (v4.y > v) { v = v4.y; ci = i4.y; }  // strict > keeps lowest
                if (v4.z > v) { v = v4.z; ci = i4.z; }
                if (v4.w > v) { v = v4.w; ci = i4.w; }
                s_red[t] = v;
                const f32x4* rp = (const f32x4*)s_red;
                const f32x4 u0 = vmax4(vmax4(rp[0],  rp[1]),  vmax4(rp[2],  rp[3]));
                const f32x4 u1 = vmax4(vmax4(rp[4],  rp[5]),  vmax4(rp[6],  rp[7]));
                const f32x4 u2 = vmax4(vmax4(rp[8],  rp[9]),  vmax4(rp[10], rp[11]));
                const f32x4 u3 = vmax4(vmax4(rp[12], rp[13]), vmax4(rp[14], rp[15]));
                const f32x4 uu = vmax4(vmax4(u0, u1), vmax4(u2, u3));
                const float gmax = fmaxf(fmaxf(uu.x, uu.y), fmaxf(uu.z, uu.w));
                const unsigned long long mb = __ballot(v == gmax);
                const int ln = (int)__ffsll(mb) - 1;
                const int g = __builtin_amdgcn_readlane(ci, ln);
                if (t == 0) s_gi = g;
            }
            __syncthreads();
            gi = s_gi;
        }
        return;
    }

    // ---------------- weight prep: 32x32 tile transpose + f16 convert --------
    int tid = bid - BB;                              // 0..351
    const float* src;
    _Float16* dh;
    int N, Kp, koff, kt, nt;
    if (tid < 32) {
        src = W1b; dh = W1bt; N = 256; Kp = KP1; koff = 0;
        kt = tid >> 3; nt = tid & 7;
    } else if (tid < 160) {
        tid -= 32;
        src = W2a; dh = W2at; N = 512; Kp = KP2; koff = 256;
        kt = tid >> 4; nt = tid & 15;
    } else {
        tid -= 160;
        src = W2b; dh = W2bt; N = 384; Kp = KP3; koff = 0;
        kt = tid / 12; nt = tid % 12;
    }
    const int k0 = kt * 32, n0 = nt * 32;
    const int tx = t & 31, ty = t >> 5;              // ty 0..7
#pragma unroll
    for (int i = 0; i < 4; ++i) {
        const int kl = ty + i * 8;
        tile[kl][tx] = src[(size_t)(k0 + kl + koff) * N + n0 + tx];
    }
    __syncthreads();
#pragma unroll
    for (int i = 0; i < 4; ++i) {
        const int nl = ty + i * 8;
        dh[(size_t)(n0 + nl) * Kp + k0 + tx] = (_Float16)tile[tx][nl];
    }
}

// ---------------------------------------------------------------------------
// kNN standalone: wave-per-seed, shfl butterfly argmin (verified rounds 3-15).
// ---------------------------------------------------------------------------
__global__ __launch_bounds__(512) void knn_kernel(
    const float* __restrict__ pos,
    const float* __restrict__ seed_pos,
    int* __restrict__ nbr)
{
    __shared__ float sx_[NN], sy_[NN], sz_[NN];
    const int blk = blockIdx.x;            // 0..127
    const int b   = blk >> 4;
    const int t   = threadIdx.x;
    const int w   = t >> 6;
    const int l   = t & 63;
    const float* p = pos + (size_t)b * NN * 3;

    for (int i = t; i < NN; i += 512) {
        sx_[i] = p[i * 3 + 0];
        sy_[i] = p[i * 3 + 1];
        sz_[i] = p[i * 3 + 2];
    }
    __syncthreads();

    const int gsid = b * SS + (blk & 15) * 8 + w;
    const float cx = seed_pos[gsid * 3 + 0];
    const float cy = seed_pos[gsid * 3 + 1];
    const float cz = seed_pos[gsid * 3 + 2];

    float d[16];
#pragma unroll
    for (int r = 0; r < 16; ++r) {
        const int i = r * 64 + l;
        const float dx = __fsub_rn(sx_[i], cx);
        const float dy = __fsub_rn(sy_[i], cy);
        const float dz = __fsub_rn(sz_[i], cz);
        d[r] = __fadd_rn(__fadd_rn(__fmul_rn(dx, dx), __fmul_rn(dy, dy)),
                         __fmul_rn(dz, dz));
    }

    for (int it = 0; it < KK; ++it) {
        float best = INFINITY;
        int bi = NN;
#pragma unroll
        for (int r = 0; r < 16; ++r) {
            if (d[r] < best) { best = d[r]; bi = r * 64 + l; }
        }
#pragma unroll
        for (int off = 1; off < 64; off <<= 1) {
            const float ov = __shfl_xor(best, off);
            const int   oi = __shfl_xor(bi, off);
            if (ov < best || (ov == best && oi < bi)) { best = ov; bi = oi; }
        }
        const int wr = bi >> 6, wl = bi & 63;
#pragma unroll
        for (int r = 0; r < 16; ++r) {
            if (r == wr && l == wl) d[r] = INFINITY;
        }
        if (l == 0) nbr[(size_t)gsid * KK + it] = bi;
    }
}

// ---------------------------------------------------------------------------
// PointConv, M=128 (4 seeds/block), 1024 threads = 16 waves, f16 operands.
// Verified round 9; byte-identical to rounds 13-15.
// ---------------------------------------------------------------------------
__global__ __launch_bounds__(1024) void conv_kernel(
    const float* __restrict__ pos,
    const float* __restrict__ seed_pos,
    const int* __restrict__ nbr,
    const float* __restrict__ W1a, const float* __restrict__ b1a,
    const float* __restrict__ b1b,
    const float* __restrict__ W2a, const float* __restrict__ b2a,
    const float* __restrict__ b2b,
    const _Float16* __restrict__ W1bt, const _Float16* __restrict__ W2at,
    const _Float16* __restrict__ W2bt,
    float* __restrict__ out)
{
    __shared__ __align__(16) unsigned char smem[144896];
    unsigned char* sBig = smem;                 // rotating region
    float* s_g    = (float*)(smem + 131072);    // [4][256]
    float* s_base = (float*)(smem + 135168);    // [4][512]
    float* s_rel  = (float*)(smem + 143360);    // [128][3]

    const int blk = blockIdx.x;                 // seeds blk*4 .. blk*4+3
    const int t   = threadIdx.x;
    const int w   = t >> 6;                     // wave 0..15
    const int l   = t & 63;
    const int lg  = l >> 4;
    const int l15 = l & 15;

    // ---- stage 0: gather rel for 128 rows (4 seeds x 32 neighbors) ----
    if (t < 128) {
        const int sl   = t >> 5;
        const int gsid = blk * 4 + sl;
        const int b    = gsid >> 7;
        const int pi   = nbr[(size_t)gsid * KK + (t & 31)];
        const float* pp = pos + ((size_t)b * NN + pi) * 3;
        s_rel[t * 3 + 0] = pp[0] - seed_pos[gsid * 3 + 0];
        s_rel[t * 3 + 1] = pp[1] - seed_pos[gsid * 3 + 1];
        s_rel[t * 3 + 2] = pp[2] - seed_pos[gsid * 3 + 2];
    }
    __syncthreads();

    // ---- stage 1: h1[128][128] = relu(rel@W1a + b1a) -> f16 swizzled ----
    {
        const int j  = t & 127;
        const int rg = t >> 7;                  // 0..7, 16 rows each
        const float w0 = W1a[j], w1 = W1a[128 + j], w2 = W1a[256 + j], bb = b1a[j];
#pragma unroll
        for (int rr = 0; rr < 16; ++rr) {
            const int row = rg * 16 + rr;
            float v = fmaf(s_rel[row * 3 + 2], w2,
                      fmaf(s_rel[row * 3 + 1], w1,
                      fmaf(s_rel[row * 3 + 0], w0, bb)));
            v = fmaxf(v, 0.0f);
            const int byte = (j * 2) ^ ((row & 7) << 4);
            *(_Float16*)(sBig + row * 256 + byte) = (_Float16)v;
        }
    }
    __syncthreads();

    // ---- GEMM1: f = h1 @ W1b (M=128,N=256,K=128); wave w owns cols w*16+ ----
    f32x4 C1[8];
#pragma unroll
    for (int m = 0; m < 8; ++m) C1[m] = (f32x4){0.f, 0.f, 0.f, 0.f};
#pragma unroll
    for (int ks = 0; ks < 4; ++ks) {
        const int ncol = w * 16 + l15;
        const f16x8 bh = *(const f16x8*)(W1bt + (size_t)ncol * KP1 + lg * 8 + ks * 32);
#pragma unroll
        for (int m = 0; m < 8; ++m) {
            const int row = m * 16 + l15;
            const int byte = (lg * 16 + ks * 64) ^ ((row & 7) << 4);
            const f16x8 ah = *(const f16x8*)(sBig + row * 256 + byte);
            C1[m] = mfma16h(ah, bh, C1[m]);
        }
    }
    // per-seed colmax -> s_g (f32)
    {
        const int col = w * 16 + l15;
        const float bias = b1b[col];
        float pm0 = -INFINITY, pm1 = -INFINITY, pm2 = -INFINITY, pm3 = -INFINITY;
#pragma unroll
        for (int m = 0; m < 8; ++m)
#pragma unroll
            for (int r = 0; r < 4; ++r) {
                const float v = C1[m][r] + bias;
                if (m < 2)      pm0 = fmaxf(pm0, v);
                else if (m < 4) pm1 = fmaxf(pm1, v);
                else if (m < 6) pm2 = fmaxf(pm2, v);
                else            pm3 = fmaxf(pm3, v);
            }
        pm0 = fmaxf(pm0, __shfl_xor(pm0, 16)); pm0 = fmaxf(pm0, __shfl_xor(pm0, 32));
        pm1 = fmaxf(pm1, __shfl_xor(pm1, 16)); pm1 = fmaxf(pm1, __shfl_xor(pm1, 32));
        pm2 = fmaxf(pm2, __shfl_xor(pm2, 16)); pm2 = fmaxf(pm2, __shfl_xor(pm2, 32));
        pm3 = fmaxf(pm3, __shfl_xor(pm3, 16)); pm3 = fmaxf(pm3, __shfl_xor(pm3, 32));
        if (lg == 0) {
            s_g[0 * 256 + col] = pm0;
            s_g[1 * 256 + col] = pm1;
            s_g[2 * 256 + col] = pm2;
            s_g[3 * 256 + col] = pm3;
        }
    }
    __syncthreads();   // all h1 reads done; s_g complete

    // ---- A2 write: f -> f16 [128][512B] (overwrites dead h1) ----
    {
        const int col = w * 16 + l15;
        const float bias = b1b[col];
#pragma unroll
        for (int m = 0; m < 8; ++m)
#pragma unroll
            for (int r = 0; r < 4; ++r) {
                const float v = C1[m][r] + bias;
                const int row = m * 16 + lg * 4 + r;
                const int byte = (col * 2) ^ ((row & 7) << 4);
                *(_Float16*)(sBig + row * 512 + byte) = (_Float16)v;
            }
    }

    // ---- base[seed][c] = b2a[c] + g_seed @ W2a[0:256]; 2 seeds/thread ----
    {
        const int col = t & 511;
        const int sp  = t >> 9;                 // 0 -> seeds 0,1 ; 1 -> seeds 2,3
        float a0 = b2a[col], a1 = b2a[col];
        const float* g0 = s_g + (sp * 2) * 256;
        const float* g1 = s_g + (sp * 2 + 1) * 256;
#pragma unroll 4
        for (int jj = 0; jj < 256; ++jj) {
            const float w_ = W2a[(size_t)jj * 512 + col];
            a0 = fmaf(g0[jj], w_, a0);
            a1 = fmaf(g1[jj], w_, a1);
        }
        s_base[(sp * 2) * 512 + col]     = a0;
        s_base[(sp * 2 + 1) * 512 + col] = a1;
    }
    __syncthreads();   // A2 + s_base complete

    // ---- GEMM2: C2 = f @ W2a[256:] (M=128,N=512,K=256); cols w*32+n*16 ----
    f32x4 C2[8][2];
#pragma unroll
    for (int m = 0; m < 8; ++m)
#pragma unroll
        for (int n = 0; n < 2; ++n) C2[m][n] = (f32x4){0.f, 0.f, 0.f, 0.f};
#pragma unroll 2
    for (int ks = 0; ks < 8; ++ks) {
        f16x8 bh[2];
#pragma unroll
        for (int n = 0; n < 2; ++n) {
            const int ncol = w * 32 + n * 16 + l15;
            bh[n] = *(const f16x8*)(W2at + (size_t)ncol * KP2 + lg * 8 + ks * 32);
        }
#pragma unroll
        for (int m = 0; m < 8; ++m) {
            const int row = m * 16 + l15;
            const int byte = (lg * 16 + ks * 64) ^ ((row & 7) << 4);
            const f16x8 ah = *(const f16x8*)(sBig + row * 512 + byte);
            C2[m][0] = mfma16h(ah, bh[0], C2[m][0]);
            C2[m][1] = mfma16h(ah, bh[1], C2[m][1]);
        }
    }
    __syncthreads();   // A2 fully read; region reusable for A3

    // ---- A3 write: h2 = relu(C2 + base) -> f16 [128][1024B] ----
#pragma unroll
    for (int n = 0; n < 2; ++n) {
        const int col = w * 32 + n * 16 + l15;
#pragma unroll
        for (int m = 0; m < 8; ++m) {
            const float bs = s_base[(m >> 1) * 512 + col];
#pragma unroll
            for (int r = 0; r < 4; ++r) {
                const float v = fmaxf(C2[m][n][r] + bs, 0.0f);
                const int row = m * 16 + lg * 4 + r;
                const int byte = (col * 2) ^ ((row & 7) << 4);
                *(_Float16*)(sBig + row * 1024 + byte) = (_Float16)v;
            }
        }
    }
    __syncthreads();   // A3 complete

    // ---- GEMM3: e = h2 @ W2b (M=128,N=384,K=512); waves 0-11, no K-split ----
    if (w < 12) {
        f32x4 C3[8][2];
#pragma unroll
        for (int m = 0; m < 8; ++m)
#pragma unroll
            for (int n = 0; n < 2; ++n) C3[m][n] = (f32x4){0.f, 0.f, 0.f, 0.f};
#pragma unroll 2
        for (int ks = 0; ks < 16; ++ks) {
            f16x8 bh[2];
#pragma unroll
            for (int n = 0; n < 2; ++n) {
                const int ncol = w * 32 + n * 16 + l15;
                bh[n] = *(const f16x8*)(W2bt + (size_t)ncol * KP3 + lg * 8 + ks * 32);
            }
#pragma unroll
            for (int m = 0; m < 8; ++m) {
                const int row = m * 16 + l15;
                const int byte = (lg * 16 + ks * 64) ^ ((row & 7) << 4);
                const f16x8 ah = *(const f16x8*)(sBig + row * 1024 + byte);
                C3[m][0] = mfma16h(ah, bh[0], C3[m][0]);
                C3[m][1] = mfma16h(ah, bh[1], C3[m][1]);
            }
        }
        // epilogue: out[seed] = colmax(e_seed) + b2b
#pragma unroll
        for (int n = 0; n < 2; ++n) {
            const int col = w * 32 + n * 16 + l15;
            float pm0 = -INFINITY, pm1 = -INFINITY, pm2 = -INFINITY, pm3 = -INFINITY;
#pragma unroll
            for (int m = 0; m < 8; ++m)
#pragma unroll
                for (int r = 0; r < 4; ++r) {
                    const float v = C3[m][n][r];
                    if (m < 2)      pm0 = fmaxf(pm0, v);
                    else if (m < 4) pm1 = fmaxf(pm1, v);
                    else if (m < 6) pm2 = fmaxf(pm2, v);
                    else            pm3 = fmaxf(pm3, v);
                }
            pm0 = fmaxf(pm0, __shfl_xor(pm0, 16)); pm0 = fmaxf(pm0, __shfl_xor(pm0, 32));
            pm1 = fmaxf(pm1, __shfl_xor(pm1, 16)); pm1 = fmaxf(pm1, __shfl_xor(pm1, 32));
            pm2 = fmaxf(pm2, __shfl_xor(pm2, 16)); pm2 = fmaxf(pm2, __shfl_xor(pm2, 32));
            pm3 = fmaxf(pm3, __shfl_xor(pm3, 16)); pm3 = fmaxf(pm3, __shfl_xor(pm3, 32));
            if (lg == 0) {
                const float bb = b2b[col];
                out[(size_t)(blk * 4 + 0) * EMB + col] = pm0 + bb;
                out[(size_t)(blk * 4 + 1) * EMB + col] = pm1 + bb;
                out[(size_t)(blk * 4 + 2) * EMB + col] = pm2 + bb;
                out[(size_t)(blk * 4 + 3) * EMB + col] = pm3 + bb;
            }
        }
    }
}

// ---------------------------------------------------------------------------
extern "C" void kernel_launch(void* const* d_in, const int* in_sizes, int n_in,
                              void* d_out, int out_size, void* d_ws, size_t ws_size,
                              hipStream_t stream)
{
    const float* pos = (const float*)d_in[0];
    const float* W1a = (const float*)d_in[2];
    const float* b1a = (const float*)d_in[3];
    const float* W1b = (const float*)d_in[4];
    const float* b1b = (const float*)d_in[5];
    const float* W2a = (const float*)d_in[6];
    const float* b2a = (const float*)d_in[7];
    const float* W2b = (const float*)d_in[8];
    const float* b2b = (const float*)d_in[9];
    float* out = (float*)d_out;

    unsigned char* ws = (unsigned char*)d_ws;
    float* seed_pos = (float*)(ws + 0);                  // 12 KB
    int*   nbr      = (int*)(ws + 16384);                // 128 KB
    _Float16* W1bt  = (_Float16*)(ws + 147456);          // [256][136] 69632 B
    _Float16* W2at  = (_Float16*)(ws + 217088);          // [512][264] 270336 B
    _Float16* W2bt  = (_Float16*)(ws + 487424);          // [384][520] 399360 B

    fps_prep_kernel<<<BB + 352, 256, 0, stream>>>(pos, seed_pos, W1b, W2a, W2b,
                                                  W1bt, W2at, W2bt);
    knn_kernel<<<BB * SS / 8, 512, 0, stream>>>(pos, seed_pos, nbr);
    conv_kernel<<<BB * SS / 4, 1024, 0, stream>>>(pos, seed_pos, nbr,
                                                  W1a, b1a, b1b, W2a, b2a, b2b,
                                                  W1bt, W2at, W2bt, out);
}

// Round 17
// 167.600 us; speedup vs baseline: 1.0770x; 1.0303x over previous
//
#include <hip/hip_runtime.h>
#include <math.h>

#define BB   8
#define NN   1024
#define SS   128
#define KK   32
#define EMB  384

// padded K strides (elements) for transposed f16 weights
#define KP1  136   // W1bt [256][136]
#define KP2  264   // W2at [512][264]
#define KP3  520   // W2bt [384][520]

// LDS float4-cloud swizzle: XOR low3 with bits3-5 (bijective involution).
#define SWZ(i) ((i) ^ (((i) >> 3) & 7))

typedef __attribute__((ext_vector_type(4))) float f32x4;
typedef __attribute__((ext_vector_type(8))) _Float16 f16x8;

__device__ __forceinline__ f32x4 mfma16h(f16x8 a, f16x8 b, f32x4 c) {
    return __builtin_amdgcn_mfma_f32_16x16x32_f16(a, b, c, 0, 0, 0);
}
__device__ __forceinline__ f32x4 vmax4(f32x4 a, f32x4 b) {
    f32x4 r;
    r.x = fmaxf(a.x, b.x); r.y = fmaxf(a.y, b.y);
    r.z = fmaxf(a.z, b.z); r.w = fmaxf(a.w, b.w);
    return r;
}

// ---------------------------------------------------------------------------
// FPS standalone (round-13 verified BEST: 88 us). 256 threads/cloud,
// VGPR-light by design (only mind[4] in regs; cloud in swizzled LDS float4).
// Reduce: thread stage -> barrier -> wave-0 (b128 pair reads, R7 broadcast
// value reduce, ballot/ffs/readlane) -> barrier. Tie semantics exact:
// strict >, ascending scan, lowest index wins.
// ---------------------------------------------------------------------------
__global__ __launch_bounds__(256) void fps_kernel(
    const float* __restrict__ pos, float* __restrict__ seed_pos)
{
    __shared__ __align__(16) float4 s_cloud4[NN];   // 16 KB, swizzled
    __shared__ __align__(16) float  s_val[256];
    __shared__ __align__(16) int    s_idx[256];
    __shared__ __align__(16) float  s_red[64];
    __shared__ int s_gi;

    const int b = blockIdx.x;
    const int t = threadIdx.x;
    const float* p = pos + (size_t)b * NN * 3;

    for (int i = t; i < NN; i += 256) {
        float4 q;
        q.x = p[i * 3 + 0];
        q.y = p[i * 3 + 1];
        q.z = p[i * 3 + 2];
        q.w = 0.0f;
        s_cloud4[SWZ(i)] = q;
    }
    __syncthreads();

    float mind[4] = {INFINITY, INFINITY, INFINITY, INFINITY};
    int gi = 0;
    for (int s = 0; s < SS; ++s) {
        const float4 sc = s_cloud4[SWZ(gi)];        // uniform broadcast read
        if (t == 0) {
            seed_pos[((size_t)b * SS + s) * 3 + 0] = sc.x;
            seed_pos[((size_t)b * SS + s) * 3 + 1] = sc.y;
            seed_pos[((size_t)b * SS + s) * 3 + 2] = sc.z;
        }
        if (s == SS - 1) break;

        // dist update + local argmax (ascending r, strict > -> lowest idx)
        float best = -INFINITY;
        int bi = 0;
#pragma unroll
        for (int r = 0; r < 4; ++r) {
            const float4 q = s_cloud4[SWZ(t * 4 + r)];
            const float dx = __fsub_rn(q.x, sc.x);
            const float dy = __fsub_rn(q.y, sc.y);
            const float dz = __fsub_rn(q.z, sc.z);
            const float d = __fadd_rn(__fadd_rn(__fmul_rn(dx, dx), __fmul_rn(dy, dy)),
                                      __fmul_rn(dz, dz));
            mind[r] = fminf(mind[r], d);
            if (mind[r] > best) { best = mind[r]; bi = t * 4 + r; }
        }
        s_val[t] = best;
        s_idx[t] = bi;
        __syncthreads();

        if (t < 64) {                                // wave 0 only
            const f32x4 v4 = *(const f32x4*)&s_val[t * 4];
            const int4  i4 = *(const int4*)&s_idx[t * 4];
            float v = v4.x; int ci = i4.x;
            if (v4.y > v) { v = v4.y; ci = i4.y; }   // strict > keeps lowest idx
            if (v4.z > v) { v = v4.z; ci = i4.z; }
            if (v4.w > v) { v = v4.w; ci = i4.w; }
            s_red[t] = v;
            const f32x4* rp = (const f32x4*)s_red;
            const f32x4 u0 = vmax4(vmax4(rp[0],  rp[1]),  vmax4(rp[2],  rp[3]));
            const f32x4 u1 = vmax4(vmax4(rp[4],  rp[5]),  vmax4(rp[6],  rp[7]));
            const f32x4 u2 = vmax4(vmax4(rp[8],  rp[9]),  vmax4(rp[10], rp[11]));
            const f32x4 u3 = vmax4(vmax4(rp[12], rp[13]), vmax4(rp[14], rp[15]));
            const f32x4 uu = vmax4(vmax4(u0, u1), vmax4(u2, u3));
            const float gmax = fmaxf(fmaxf(uu.x, uu.y), fmaxf(uu.z, uu.w));
            const unsigned long long mb = __ballot(v == gmax);
            const int ln = (int)__ffsll(mb) - 1;
            const int g = __builtin_amdgcn_readlane(ci, ln);
            if (t == 0) s_gi = g;
        }
        __syncthreads();
        gi = s_gi;
    }
}

// ---------------------------------------------------------------------------
// knn_prep: blocks 0..127 = kNN (verified rounds 3-16, logic untouched);
// blocks 128..303 = weight transpose + f16 convert, 2 tiles per 512-thr block.
// ---------------------------------------------------------------------------
__global__ __launch_bounds__(512) void knn_prep_kernel(
    const float* __restrict__ pos,
    const float* __restrict__ seed_pos,
    int* __restrict__ nbr,
    const float* __restrict__ W1b, const float* __restrict__ W2a,
    const float* __restrict__ W2b,
    _Float16* __restrict__ W1bt, _Float16* __restrict__ W2at,
    _Float16* __restrict__ W2bt)
{
    __shared__ float sx_[NN], sy_[NN], sz_[NN];
    __shared__ float tile[2][32][33];
    const int bid = blockIdx.x;
    const int t   = threadIdx.x;

    if (bid < 128) {
        const int blk = bid;
        const int b   = blk >> 4;
        const int w   = t >> 6;
        const int l   = t & 63;
        const float* p = pos + (size_t)b * NN * 3;

        for (int i = t; i < NN; i += 512) {
            sx_[i] = p[i * 3 + 0];
            sy_[i] = p[i * 3 + 1];
            sz_[i] = p[i * 3 + 2];
        }
        __syncthreads();

        const int gsid = b * SS + (blk & 15) * 8 + w;
        const float cx = seed_pos[gsid * 3 + 0];
        const float cy = seed_pos[gsid * 3 + 1];
        const float cz = seed_pos[gsid * 3 + 2];

        float d[16];
#pragma unroll
        for (int r = 0; r < 16; ++r) {
            const int i = r * 64 + l;
            const float dx = __fsub_rn(sx_[i], cx);
            const float dy = __fsub_rn(sy_[i], cy);
            const float dz = __fsub_rn(sz_[i], cz);
            d[r] = __fadd_rn(__fadd_rn(__fmul_rn(dx, dx), __fmul_rn(dy, dy)),
                             __fmul_rn(dz, dz));
        }

        for (int it = 0; it < KK; ++it) {
            float best = INFINITY;
            int bi = NN;
#pragma unroll
            for (int r = 0; r < 16; ++r) {
                if (d[r] < best) { best = d[r]; bi = r * 64 + l; }
            }
#pragma unroll
            for (int off = 1; off < 64; off <<= 1) {
                const float ov = __shfl_xor(best, off);
                const int   oi = __shfl_xor(bi, off);
                if (ov < best || (ov == best && oi < bi)) { best = ov; bi = oi; }
            }
            const int wr = bi >> 6, wl = bi & 63;
#pragma unroll
            for (int r = 0; r < 16; ++r) {
                if (r == wr && l == wl) d[r] = INFINITY;
            }
            if (l == 0) nbr[(size_t)gsid * KK + it] = bi;
        }
        return;
    }

    // ---------------- weight prep: 2 tiles per block ----------------
    const int half = t >> 8;
    const int tt   = t & 255;
    int tid = (bid - 128) * 2 + half;
    const float* src;
    _Float16* dh;
    int N, Kp, koff, kt, nt;
    if (tid < 32) {
        src = W1b; dh = W1bt; N = 256; Kp = KP1; koff = 0;
        kt = tid >> 3; nt = tid & 7;
    } else if (tid < 160) {
        tid -= 32;
        src = W2a; dh = W2at; N = 512; Kp = KP2; koff = 256;
        kt = tid >> 4; nt = tid & 15;
    } else {
        tid -= 160;
        src = W2b; dh = W2bt; N = 384; Kp = KP3; koff = 0;
        kt = tid / 12; nt = tid % 12;
    }
    const int k0 = kt * 32, n0 = nt * 32;
    const int tx = tt & 31, ty = tt >> 5;
#pragma unroll
    for (int i = 0; i < 4; ++i) {
        const int kl = ty + i * 8;
        tile[half][kl][tx] = src[(size_t)(k0 + kl + koff) * N + n0 + tx];
    }
    __syncthreads();
#pragma unroll
    for (int i = 0; i < 4; ++i) {
        const int nl = ty + i * 8;
        dh[(size_t)(n0 + nl) * Kp + k0 + tx] = (_Float16)tile[half][tx][nl];
    }
}

// ---------------------------------------------------------------------------
// PointConv, M=128 (4 seeds/block), 1024 threads = 16 waves, f16 operands.
// Verified round 9; byte-identical to rounds 13-16.
// ---------------------------------------------------------------------------
__global__ __launch_bounds__(1024) void conv_kernel(
    const float* __restrict__ pos,
    const float* __restrict__ seed_pos,
    const int* __restrict__ nbr,
    const float* __restrict__ W1a, const float* __restrict__ b1a,
    const float* __restrict__ b1b,
    const float* __restrict__ W2a, const float* __restrict__ b2a,
    const float* __restrict__ b2b,
    const _Float16* __restrict__ W1bt, const _Float16* __restrict__ W2at,
    const _Float16* __restrict__ W2bt,
    float* __restrict__ out)
{
    __shared__ __align__(16) unsigned char smem[144896];
    unsigned char* sBig = smem;                 // rotating region
    float* s_g    = (float*)(smem + 131072);    // [4][256]
    float* s_base = (float*)(smem + 135168);    // [4][512]
    float* s_rel  = (float*)(smem + 143360);    // [128][3]

    const int blk = blockIdx.x;                 // seeds blk*4 .. blk*4+3
    const int t   = threadIdx.x;
    const int w   = t >> 6;                     // wave 0..15
    const int l   = t & 63;
    const int lg  = l >> 4;
    const int l15 = l & 15;

    // ---- stage 0: gather rel for 128 rows (4 seeds x 32 neighbors) ----
    if (t < 128) {
        const int sl   = t >> 5;
        const int gsid = blk * 4 + sl;
        const int b    = gsid >> 7;
        const int pi   = nbr[(size_t)gsid * KK + (t & 31)];
        const float* pp = pos + ((size_t)b * NN + pi) * 3;
        s_rel[t * 3 + 0] = pp[0] - seed_pos[gsid * 3 + 0];
        s_rel[t * 3 + 1] = pp[1] - seed_pos[gsid * 3 + 1];
        s_rel[t * 3 + 2] = pp[2] - seed_pos[gsid * 3 + 2];
    }
    __syncthreads();

    // ---- stage 1: h1[128][128] = relu(rel@W1a + b1a) -> f16 swizzled ----
    {
        const int j  = t & 127;
        const int rg = t >> 7;                  // 0..7, 16 rows each
        const float w0 = W1a[j], w1 = W1a[128 + j], w2 = W1a[256 + j], bb = b1a[j];
#pragma unroll
        for (int rr = 0; rr < 16; ++rr) {
            const int row = rg * 16 + rr;
            float v = fmaf(s_rel[row * 3 + 2], w2,
                      fmaf(s_rel[row * 3 + 1], w1,
                      fmaf(s_rel[row * 3 + 0], w0, bb)));
            v = fmaxf(v, 0.0f);
            const int byte = (j * 2) ^ ((row & 7) << 4);
            *(_Float16*)(sBig + row * 256 + byte) = (_Float16)v;
        }
    }
    __syncthreads();

    // ---- GEMM1: f = h1 @ W1b (M=128,N=256,K=128); wave w owns cols w*16+ ----
    f32x4 C1[8];
#pragma unroll
    for (int m = 0; m < 8; ++m) C1[m] = (f32x4){0.f, 0.f, 0.f, 0.f};
#pragma unroll
    for (int ks = 0; ks < 4; ++ks) {
        const int ncol = w * 16 + l15;
        const f16x8 bh = *(const f16x8*)(W1bt + (size_t)ncol * KP1 + lg * 8 + ks * 32);
#pragma unroll
        for (int m = 0; m < 8; ++m) {
            const int row = m * 16 + l15;
            const int byte = (lg * 16 + ks * 64) ^ ((row & 7) << 4);
            const f16x8 ah = *(const f16x8*)(sBig + row * 256 + byte);
            C1[m] = mfma16h(ah, bh, C1[m]);
        }
    }
    // per-seed colmax -> s_g (f32)
    {
        const int col = w * 16 + l15;
        const float bias = b1b[col];
        float pm0 = -INFINITY, pm1 = -INFINITY, pm2 = -INFINITY, pm3 = -INFINITY;
#pragma unroll
        for (int m = 0; m < 8; ++m)
#pragma unroll
            for (int r = 0; r < 4; ++r) {
                const float v = C1[m][r] + bias;
                if (m < 2)      pm0 = fmaxf(pm0, v);
                else if (m < 4) pm1 = fmaxf(pm1, v);
                else if (m < 6) pm2 = fmaxf(pm2, v);
                else            pm3 = fmaxf(pm3, v);
            }
        pm0 = fmaxf(pm0, __shfl_xor(pm0, 16)); pm0 = fmaxf(pm0, __shfl_xor(pm0, 32));
        pm1 = fmaxf(pm1, __shfl_xor(pm1, 16)); pm1 = fmaxf(pm1, __shfl_xor(pm1, 32));
        pm2 = fmaxf(pm2, __shfl_xor(pm2, 16)); pm2 = fmaxf(pm2, __shfl_xor(pm2, 32));
        pm3 = fmaxf(pm3, __shfl_xor(pm3, 16)); pm3 = fmaxf(pm3, __shfl_xor(pm3, 32));
        if (lg == 0) {
            s_g[0 * 256 + col] = pm0;
            s_g[1 * 256 + col] = pm1;
            s_g[2 * 256 + col] = pm2;
            s_g[3 * 256 + col] = pm3;
        }
    }
    __syncthreads();   // all h1 reads done; s_g complete

    // ---- A2 write: f -> f16 [128][512B] (overwrites dead h1) ----
    {
        const int col = w * 16 + l15;
        const float bias = b1b[col];
#pragma unroll
        for (int m = 0; m < 8; ++m)
#pragma unroll
            for (int r = 0; r < 4; ++r) {
                const float v = C1[m][r] + bias;
                const int row = m * 16 + lg * 4 + r;
                const int byte = (col * 2) ^ ((row & 7) << 4);
                *(_Float16*)(sBig + row * 512 + byte) = (_Float16)v;
            }
    }

    // ---- base[seed][c] = b2a[c] + g_seed @ W2a[0:256]; 2 seeds/thread ----
    {
        const int col = t & 511;
        const int sp  = t >> 9;                 // 0 -> seeds 0,1 ; 1 -> seeds 2,3
        float a0 = b2a[col], a1 = b2a[col];
        const float* g0 = s_g + (sp * 2) * 256;
        const float* g1 = s_g + (sp * 2 + 1) * 256;
#pragma unroll 4
        for (int jj = 0; jj < 256; ++jj) {
            const float w_ = W2a[(size_t)jj * 512 + col];
            a0 = fmaf(g0[jj], w_, a0);
            a1 = fmaf(g1[jj], w_, a1);
        }
        s_base[(sp * 2) * 512 + col]     = a0;
        s_base[(sp * 2 + 1) * 512 + col] = a1;
    }
    __syncthreads();   // A2 + s_base complete

    // ---- GEMM2: C2 = f @ W2a[256:] (M=128,N=512,K=256); cols w*32+n*16 ----
    f32x4 C2[8][2];
#pragma unroll
    for (int m = 0; m < 8; ++m)
#pragma unroll
        for (int n = 0; n < 2; ++n) C2[m][n] = (f32x4){0.f, 0.f, 0.f, 0.f};
#pragma unroll 2
    for (int ks = 0; ks < 8; ++ks) {
        f16x8 bh[2];
#pragma unroll
        for (int n = 0; n < 2; ++n) {
            const int ncol = w * 32 + n * 16 + l15;
            bh[n] = *(const f16x8*)(W2at + (size_t)ncol * KP2 + lg * 8 + ks * 32);
        }
#pragma unroll
        for (int m = 0; m < 8; ++m) {
            const int row = m * 16 + l15;
            const int byte = (lg * 16 + ks * 64) ^ ((row & 7) << 4);
            const f16x8 ah = *(const f16x8*)(sBig + row * 512 + byte);
            C2[m][0] = mfma16h(ah, bh[0], C2[m][0]);
            C2[m][1] = mfma16h(ah, bh[1], C2[m][1]);
        }
    }
    __syncthreads();   // A2 fully read; region reusable for A3

    // ---- A3 write: h2 = relu(C2 + base) -> f16 [128][1024B] ----
#pragma unroll
    for (int n = 0; n < 2; ++n) {
        const int col = w * 32 + n * 16 + l15;
#pragma unroll
        for (int m = 0; m < 8; ++m) {
            const float bs = s_base[(m >> 1) * 512 + col];
#pragma unroll
            for (int r = 0; r < 4; ++r) {
                const float v = fmaxf(C2[m][n][r] + bs, 0.0f);
                const int row = m * 16 + lg * 4 + r;
                const int byte = (col * 2) ^ ((row & 7) << 4);
                *(_Float16*)(sBig + row * 1024 + byte) = (_Float16)v;
            }
        }
    }
    __syncthreads();   // A3 complete

    // ---- GEMM3: e = h2 @ W2b (M=128,N=384,K=512); waves 0-11, no K-split ----
    if (w < 12) {
        f32x4 C3[8][2];
#pragma unroll
        for (int m = 0; m < 8; ++m)
#pragma unroll
            for (int n = 0; n < 2; ++n) C3[m][n] = (f32x4){0.f, 0.f, 0.f, 0.f};
#pragma unroll 2
        for (int ks = 0; ks < 16; ++ks) {
            f16x8 bh[2];
#pragma unroll
            for (int n = 0; n < 2; ++n) {
                const int ncol = w * 32 + n * 16 + l15;
                bh[n] = *(const f16x8*)(W2bt + (size_t)ncol * KP3 + lg * 8 + ks * 32);
            }
#pragma unroll
            for (int m = 0; m < 8; ++m) {
                const int row = m * 16 + l15;
                const int byte = (lg * 16 + ks * 64) ^ ((row & 7) << 4);
                const f16x8 ah = *(const f16x8*)(sBig + row * 1024 + byte);
                C3[m][0] = mfma16h(ah, bh[0], C3[m][0]);
                C3[m][1] = mfma16h(ah, bh[1], C3[m][1]);
            }
        }
        // epilogue: out[seed] = colmax(e_seed) + b2b
#pragma unroll
        for (int n = 0; n < 2; ++n) {
            const int col = w * 32 + n * 16 + l15;
            float pm0 = -INFINITY, pm1 = -INFINITY, pm2 = -INFINITY, pm3 = -INFINITY;
#pragma unroll
            for (int m = 0; m < 8; ++m)
#pragma unroll
                for (int r = 0; r < 4; ++r) {
                    const float v = C3[m][n][r];
                    if (m < 2)      pm0 = fmaxf(pm0, v);
                    else if (m < 4) pm1 = fmaxf(pm1, v);
                    else if (m < 6) pm2 = fmaxf(pm2, v);
                    else            pm3 = fmaxf(pm3, v);
                }
            pm0 = fmaxf(pm0, __shfl_xor(pm0, 16)); pm0 = fmaxf(pm0, __shfl_xor(pm0, 32));
            pm1 = fmaxf(pm1, __shfl_xor(pm1, 16)); pm1 = fmaxf(pm1, __shfl_xor(pm1, 32));
            pm2 = fmaxf(pm2, __shfl_xor(pm2, 16)); pm2 = fmaxf(pm2, __shfl_xor(pm2, 32));
            pm3 = fmaxf(pm3, __shfl_xor(pm3, 16)); pm3 = fmaxf(pm3, __shfl_xor(pm3, 32));
            if (lg == 0) {
                const float bb = b2b[col];
                out[(size_t)(blk * 4 + 0) * EMB + col] = pm0 + bb;
                out[(size_t)(blk * 4 + 1) * EMB + col] = pm1 + bb;
                out[(size_t)(blk * 4 + 2) * EMB + col] = pm2 + bb;
                out[(size_t)(blk * 4 + 3) * EMB + col] = pm3 + bb;
            }
        }
    }
}

// ---------------------------------------------------------------------------
extern "C" void kernel_launch(void* const* d_in, const int* in_sizes, int n_in,
                              void* d_out, int out_size, void* d_ws, size_t ws_size,
                              hipStream_t stream)
{
    const float* pos = (const float*)d_in[0];
    const float* W1a = (const float*)d_in[2];
    const float* b1a = (const float*)d_in[3];
    const float* W1b = (const float*)d_in[4];
    const float* b1b = (const float*)d_in[5];
    const float* W2a = (const float*)d_in[6];
    const float* b2a = (const float*)d_in[7];
    const float* W2b = (const float*)d_in[8];
    const float* b2b = (const float*)d_in[9];
    float* out = (float*)d_out;

    unsigned char* ws = (unsigned char*)d_ws;
    float* seed_pos = (float*)(ws + 0);                  // 12 KB
    int*   nbr      = (int*)(ws + 16384);                // 128 KB
    _Float16* W1bt  = (_Float16*)(ws + 147456);          // [256][136] 69632 B
    _Float16* W2at  = (_Float16*)(ws + 217088);          // [512][264] 270336 B
    _Float16* W2bt  = (_Float16*)(ws + 487424);          // [384][520] 399360 B

    fps_kernel<<<BB, 256, 0, stream>>>(pos, seed_pos);
    knn_prep_kernel<<<128 + 176, 512, 0, stream>>>(pos, seed_pos, nbr,
                                                   W1b, W2a, W2b,
                                                   W1bt, W2at, W2bt);
    conv_kernel<<<BB * SS / 4, 1024, 0, stream>>>(pos, seed_pos, nbr,
                                                  W1a, b1a, b1b, W2a, b2a, b2b,
                                                  W1bt, W2at, W2bt, out);
}